// Round 11
// baseline (104.547 us; speedup 1.0000x reference)
//
#include <hip/hip_runtime.h>

#define B 8
#define T 512
#define TEMP_IN 32
#define STAT_IN 16
#define TEMP_H 64
#define STAT_H 32
#define ATTN_H 32
#define N_CLS 2
#define BN_INV 0.99999500003749969f
// 256 blocks x 512 threads; each block = 2 tiles of 8 query rows (16 rows)
#define NBLK 256
#define NT2  32    // tile-pairs per batch

struct KP {
    const float *x_temp, *x_stat, *t;
    const int* lengths;
    const float *aw0, *ab0, *ag, *abeta, *aw1, *ab1;
    const float *tw, *tb, *tg, *tbeta;
    const float *sw, *sb, *sg, *sbeta;
    const float *lw_t, *lb_t, *lg_t, *lbeta_t;
    const float *lw_s, *lb_s, *lg_s, *lbeta_s;
    const float *cw, *cb;
    float *XL, *XL2;
    unsigned long long* cand;   // [B*32*8]  (64B-padded candidate per block)
    unsigned *f1, *f2;          // [B*32*16] (64B-padded flag per block, per sync)
    unsigned *arr;              // [B*16]    (64B-padded last-arriver counter)
    float *out, *outmax;
};

__device__ __forceinline__ float lrelu(float x) {
    return fmaxf(x, 0.01f * x);
}
__device__ __forceinline__ float wave_max(float x) {
    #pragma unroll
    for (int o = 32; o > 0; o >>= 1) x = fmaxf(x, __shfl_xor(x, o));
    return x;
}
__device__ __forceinline__ float wave_sum(float x) {
    #pragma unroll
    for (int o = 32; o > 0; o >>= 1) x += __shfl_xor(x, o);
    return x;
}
__device__ __forceinline__ unsigned ordf(float f) {
    unsigned u = __float_as_uint(f);
    return (u & 0x80000000u) ? ~u : (u | 0x80000000u);
}
__device__ __forceinline__ void stg_llc(float* p, float v) {
    __hip_atomic_store(p, v, __ATOMIC_RELAXED, __HIP_MEMORY_SCOPE_AGENT);
}
__device__ __forceinline__ float ldg_llc(const float* p) {
    return __hip_atomic_load(p, __ATOMIC_RELAXED, __HIP_MEMORY_SCOPE_AGENT);
}
__device__ __forceinline__ void drain_vm() {
    asm volatile("s_waitcnt vmcnt(0)" ::: "memory");
}
__device__ __forceinline__ void fence_acq_wg() {
    __builtin_amdgcn_fence(__ATOMIC_ACQUIRE, "workgroup");
}

struct Shm {
    float att[2][8][T];               // 32 KB
    union {                           // 16 KB (part: attn; fr: front scratch)
        float part[2][4][8][TEMP_H];
        struct { float xr[8][TEMP_IN]; float h0s[8][TEMP_H + STAT_H]; } fr;
    } u;
    float xi[2][8][TEMP_H];           // 4 KB
    float x1[2][8][TEMP_H];           // 4 KB
    float t_s[T];                     // 2 KB
    float s_w[3 * ATTN_H + 1];
    float xs[3][STAT_H];
    float o_rc[16][2];
    int lastf;
};

// ---- batch sync (width 32): waitcnt + own-flag store; relaxed spin + wg acquire ----
__device__ __forceinline__ void publish(unsigned* f) {
    drain_vm();
    __syncthreads();
    if (threadIdx.x == 0)
        __hip_atomic_store(f, 1u, __ATOMIC_RELAXED, __HIP_MEMORY_SCOPE_AGENT);
}
__device__ __forceinline__ void wait_batch(const unsigned* fbase, int tid) {
    if (tid < NT2) {
        const unsigned* p = fbase + tid * 16;
        while (__hip_atomic_load(p, __ATOMIC_RELAXED, __HIP_MEMORY_SCOPE_AGENT) == 0u)
            __builtin_amdgcn_s_sleep(4);
    }
    __syncthreads();
    fence_acq_wg();
}

// ---- front MLP: encoder + layer0 for this block's 16 rows -> XL (LLC) ----
__device__ __forceinline__ void front(const KP& P, Shm& S, int b, int i0b, int len,
                                      int lane, int wave) {
    #pragma unroll
    for (int p = 0; p < 2; ++p) {
        int r = p * 8 + wave;           // 0..15
        int i = i0b + r;
        int row = b * T + i;
        if (lane < TEMP_IN) S.u.fr.xr[wave][lane] = P.x_temp[row * TEMP_IN + lane];
        __syncthreads();
        float acc = P.tb[lane];
        #pragma unroll
        for (int k = 0; k < TEMP_IN; ++k) acc += S.u.fr.xr[wave][k] * P.tw[k * TEMP_H + lane];
        acc = acc * (P.tg[lane] * BN_INV) + P.tbeta[lane];
        S.u.fr.h0s[wave][lane] = lrelu(acc);
        if (lane < STAT_H) S.u.fr.h0s[wave][TEMP_H + lane] = S.xs[0][lane];
        __syncthreads();
        float a2 = P.lb_t[lane];
        #pragma unroll
        for (int k = 0; k < TEMP_H + STAT_H; ++k) a2 += S.u.fr.h0s[wave][k] * P.lw_t[k * TEMP_H + lane];
        a2 = a2 * (P.lg_t[lane] * BN_INV) + P.lbeta_t[lane];
        a2 = lrelu(a2);
        stg_llc(&P.XL[(size_t)row * TEMP_H + lane], (i < len) ? a2 : 0.f);
        __syncthreads();
    }
}

// ---- temp-attn softmax rows for this wave's tile -> registers ----
__device__ __forceinline__ void temp_compute(Shm& S, float tmpv[2][8], float inv_dt,
                                             int i0s, int len, int lane, int swave) {
    float ab1v = S.s_w[3 * ATTN_H];
    #pragma unroll
    for (int rr = 0; rr < 2; ++rr) {
        int r = swave + rr * 4;
        float ti = S.t_s[i0s + r];
        float a[8], dtq[8];
        #pragma unroll
        for (int q = 0; q < 8; ++q) {
            dtq[q] = (S.t_s[lane + q * 64] - ti) * inv_dt;
            a[q] = ab1v;
        }
        #pragma unroll 4
        for (int k = 0; k < ATTN_H; ++k) {
            float Wk = S.s_w[k];
            float Ck = S.s_w[ATTN_H + k];
            float w1k = S.s_w[2 * ATTN_H + k];
            #pragma unroll
            for (int q = 0; q < 8; ++q) {
                float h = dtq[q] * Wk + Ck;
                h = fmaxf(h, 0.01f * h);
                a[q] += h * w1k;
            }
        }
        float m2 = -1e30f;
        #pragma unroll
        for (int q = 0; q < 8; ++q) {
            int j = lane + q * 64;
            a[q] = (j < len) ? a[q] : -9e8f;
            m2 = fmaxf(m2, a[q]);
        }
        m2 = wave_max(m2);
        float s2 = 0.f;
        #pragma unroll
        for (int q = 0; q < 8; ++q) { a[q] = __expf(a[q] - m2); s2 += a[q]; }
        s2 = wave_sum(s2);
        float inv2 = 1.0f / s2;
        #pragma unroll
        for (int q = 0; q < 8; ++q) tmpv[rr][q] = a[q] * inv2;
    }
}

// ---- attention core (both tiles); EPI 0: layer1-MLP -> XL2 (+ stage xi);
//      EPI 1: classifier + argmax.  LOAD_XI: fetch query rows from src. ----
template <int EPI, bool LOAD_XI>
__device__ __forceinline__ void attn_core(const KP& P, Shm& S, const float* src,
                                          const float tmpv[2][8],
                                          int b, int i0b, int len,
                                          int tid, int lane, int side, int stid, int swave,
                                          int blk_id) {
    int i0s = i0b + side * 8;
    if (LOAD_XI) {
        for (int idx = stid; idx < 8 * TEMP_H; idx += 256)
            S.xi[side][idx >> 6][idx & 63] =
                src[((size_t)(b * T + i0s + (idx >> 6))) * TEMP_H + (idx & 63)];
    }
    __syncthreads();
    // qk
    for (int j = stid; j < T; j += 256) {
        const float4* xj4 = reinterpret_cast<const float4*>(&src[((size_t)(b * T + j)) * TEMP_H]);
        float acc[8];
        #pragma unroll
        for (int r = 0; r < 8; ++r) acc[r] = 0.f;
        #pragma unroll
        for (int c4 = 0; c4 < TEMP_H / 4; ++c4) {
            float4 xv = xj4[c4];
            #pragma unroll
            for (int r = 0; r < 8; ++r) {
                float4 xi4 = *reinterpret_cast<const float4*>(&S.xi[side][r][c4 * 4]);
                acc[r] += xi4.x * xv.x + xi4.y * xv.y + xi4.z * xv.z + xi4.w * xv.w;
            }
        }
        #pragma unroll
        for (int r = 0; r < 8; ++r) S.att[side][r][j] = acc[r] * 0.125f;
    }
    __syncthreads();
    // softmax(qk) + register temp_attn, mask_j
    #pragma unroll
    for (int rr = 0; rr < 2; ++rr) {
        int r = swave + rr * 4;
        float v[8];
        float m = -1e30f;
        #pragma unroll
        for (int q = 0; q < 8; ++q) { v[q] = S.att[side][r][lane + q * 64]; m = fmaxf(m, v[q]); }
        m = wave_max(m);
        float s = 0.f;
        #pragma unroll
        for (int q = 0; q < 8; ++q) { v[q] = __expf(v[q] - m); s += v[q]; }
        s = wave_sum(s);
        float invs = 1.0f / s;
        #pragma unroll
        for (int q = 0; q < 8; ++q) {
            int j = lane + q * 64;
            S.att[side][r][j] = (j < len) ? (v[q] * invs + tmpv[rr][q]) : 0.f;
        }
    }
    __syncthreads();
    // PV
    float acc2[8];
    #pragma unroll
    for (int r = 0; r < 8; ++r) acc2[r] = 0.f;
    {
        const float* srow = src + (size_t)b * T * TEMP_H + lane;
        int j0 = swave * 128;
        for (int g = 0; g < 32; ++g) {
            int j = j0 + g * 4;
            float xv0 = srow[(size_t)(j + 0) * TEMP_H];
            float xv1 = srow[(size_t)(j + 1) * TEMP_H];
            float xv2 = srow[(size_t)(j + 2) * TEMP_H];
            float xv3 = srow[(size_t)(j + 3) * TEMP_H];
            #pragma unroll
            for (int r = 0; r < 8; ++r) {
                float4 a4 = *reinterpret_cast<const float4*>(&S.att[side][r][j]);
                acc2[r] += a4.x * xv0 + a4.y * xv1 + a4.z * xv2 + a4.w * xv3;
            }
        }
    }
    #pragma unroll
    for (int r = 0; r < 8; ++r) S.u.part[side][swave][r][lane] = acc2[r];
    __syncthreads();
    for (int idx = stid; idx < 8 * TEMP_H; idx += 256) {
        int r = idx >> 6, cc = idx & 63;
        float sum = S.u.part[side][0][r][cc] + S.u.part[side][1][r][cc]
                  + S.u.part[side][2][r][cc] + S.u.part[side][3][r][cc];
        S.x1[side][r][cc] = ((i0s + r) < len) ? sum : 0.f;
    }
    __syncthreads();

    if (EPI == 0) {
        const float* lw1    = P.lw_t + (TEMP_H + STAT_H) * TEMP_H;
        const float* lb1    = P.lb_t + TEMP_H;
        const float* lg1    = P.lg_t + TEMP_H;
        const float* lbeta1 = P.lbeta_t + TEMP_H;
        #pragma unroll
        for (int rr = 0; rr < 2; ++rr) {
            int r = swave * 2 + rr;
            int i = i0s + r;
            float acc = lb1[lane];
            #pragma unroll
            for (int k = 0; k < TEMP_H; ++k) acc += S.x1[side][r][k] * lw1[k * TEMP_H + lane];
            #pragma unroll
            for (int k = 0; k < STAT_H; ++k) acc += S.xs[1][k] * lw1[(TEMP_H + k) * TEMP_H + lane];
            acc = acc * (lg1[lane] * BN_INV) + lbeta1[lane];
            acc = lrelu(acc);
            float vout = (i < len) ? acc : 0.f;
            stg_llc(&P.XL2[((size_t)(b * T + i)) * TEMP_H + lane], vout);
            S.xi[side][r][lane] = vout;   // stage 2's query rows — skip the reload
        }
    } else {
        if (stid < 8 * N_CLS) {
            int r = stid >> 1, cls = stid & 1;
            int i = i0s + r;
            float o = P.cb[cls];
            #pragma unroll
            for (int k = 0; k < TEMP_H; ++k) o += S.x1[side][r][k] * P.cw[k * N_CLS + cls];
            #pragma unroll
            for (int k = 0; k < STAT_H; ++k) o += S.xs[2][k] * P.cw[(TEMP_H + k) * N_CLS + cls];
            if (i >= len) o = 0.f;
            stg_llc(&P.out[((size_t)(b * T + i)) * N_CLS + cls], o);
            S.o_rc[side * 8 + r][cls] = o;
        }
        __syncthreads();
        if (tid == 0) {
            float best = -3e30f; int bi = i0b;
            for (int r = 0; r < 16; ++r) {
                int i = i0b + r;
                float diff = (i < len) ? (S.o_rc[r][1] - S.o_rc[r][0]) : -1e30f;
                if (diff > best) { best = diff; bi = i; }
            }
            unsigned long long pack =
                ((unsigned long long)ordf(best) << 32) | (unsigned)(~(unsigned)bi);
            __hip_atomic_store(&P.cand[blk_id * 8], pack,
                               __ATOMIC_RELAXED, __HIP_MEMORY_SCOPE_AGENT);
            drain_vm();
            unsigned old = __hip_atomic_fetch_add(&P.arr[b * 16], 1u,
                                                  __ATOMIC_RELAXED, __HIP_MEMORY_SCOPE_AGENT);
            S.lastf = (old == (NT2 - 1)) ? 1 : 0;
        }
        __syncthreads();
        if (S.lastf) {
            fence_acq_wg();
            if (tid < NT2) {
                unsigned long long c = __hip_atomic_load(&P.cand[(b * NT2 + tid) * 8],
                                                         __ATOMIC_RELAXED, __HIP_MEMORY_SCOPE_AGENT);
                #pragma unroll
                for (int o = 16; o > 0; o >>= 1) {
                    unsigned long long oc = __shfl_xor(c, o);
                    c = (oc > c) ? oc : c;
                }
                if (tid == 0) {
                    int idx = (int)(~(unsigned)(c & 0xffffffffu));
                    float o0 = ldg_llc(&P.out[((size_t)(b * T + idx)) * N_CLS + 0]);
                    float o1 = ldg_llc(&P.out[((size_t)(b * T + idx)) * N_CLS + 1]);
                    stg_llc(&P.outmax[b * 2 + 0], o0);
                    stg_llc(&P.outmax[b * 2 + 1], o1);
                }
            }
        }
    }
}

// PHASE: 0 = front only, 1 = stage A only, 2 = stage B only, 3 = fully fused
template <int PHASE>
__global__ void __launch_bounds__(512) k_run(KP P) {
    __shared__ Shm S;
    int tid = threadIdx.x;             // 0..511
    int lane = tid & 63, wave = tid >> 6;          // wave 0..7
    int side = wave >> 2, swave = wave & 3;        // tile side, wave-within-tile
    int stid = tid & 255;                          // thread-within-tile
    int blk = blockIdx.x;
    int b = blk & 7, t2 = blk >> 3;                // XCD-affinity swizzle
    int blk_id = b * NT2 + t2;
    int i0b = t2 * 16;
    int len = P.lengths[b];
    float tmpv[2][8];

    // xs0 (stat encoder)
    if (tid < STAT_H) {
        float acc = P.sb[tid];
        #pragma unroll
        for (int k = 0; k < STAT_IN; ++k) acc += P.x_stat[b * STAT_IN + k] * P.sw[k * STAT_H + tid];
        acc = acc * (P.sg[tid] * BN_INV) + P.sbeta[tid];
        S.xs[0][tid] = lrelu(acc);
    }
    __syncthreads();

    if (PHASE == 0 || PHASE == 3) front(P, S, b, i0b, len, lane, wave);
    if (PHASE == 3) publish(&P.f1[blk_id * 16]);

    if (PHASE != 0) {
        if (tid < ATTN_H) {
            float g = P.ag[tid] * BN_INV;
            S.s_w[tid]              = P.aw0[tid] * g;
            S.s_w[ATTN_H + tid]     = P.ab0[tid] * g + P.abeta[tid];
            S.s_w[2 * ATTN_H + tid] = P.aw1[tid];
        }
        if (tid == 0) S.s_w[3 * ATTN_H] = P.ab1[0];
        S.t_s[tid] = P.t[b * T + tid];
        float d = P.t[(lane & 7) * T + (T - 1)] - P.t[(lane & 7) * T];
        d = wave_max(d);
        float inv_dt = 1.0f / (d + 1e-8f);
        __syncthreads();
        if (tid < STAT_H) {   // xs1
            float a2 = P.lb_s[tid];
            #pragma unroll
            for (int k = 0; k < STAT_H; ++k) a2 += S.xs[0][k] * P.lw_s[k * STAT_H + tid];
            a2 = a2 * (P.lg_s[tid] * BN_INV) + P.lbeta_s[tid];
            S.xs[1][tid] = lrelu(a2);
        }
        __syncthreads();
        if (tid < STAT_H) {   // xs2
            float a2 = P.lb_s[STAT_H + tid];
            #pragma unroll
            for (int k = 0; k < STAT_H; ++k) a2 += S.xs[1][k] * P.lw_s[(STAT_H + k) * STAT_H + tid];
            a2 = a2 * (P.lg_s[STAT_H + tid] * BN_INV) + P.lbeta_s[STAT_H + tid];
            S.xs[2][tid] = lrelu(a2);
        }
        __syncthreads();
        temp_compute(S, tmpv, inv_dt, i0b + side * 8, len, lane, swave);  // overlaps f1 wait
        __syncthreads();
    }

    if (PHASE == 3) wait_batch(P.f1 + b * NT2 * 16, tid);
    if (PHASE == 1 || PHASE == 3)
        attn_core<0, true>(P, S, P.XL, tmpv, b, i0b, len, tid, lane, side, stid, swave, blk_id);
    if (PHASE == 3) {
        publish(&P.f2[blk_id * 16]);
        wait_batch(P.f2 + b * NT2 * 16, tid);
        attn_core<1, false>(P, S, P.XL2, tmpv, b, i0b, len, tid, lane, side, stid, swave, blk_id);
    } else if (PHASE == 2) {
        attn_core<1, true>(P, S, P.XL2, tmpv, b, i0b, len, tid, lane, side, stid, swave, blk_id);
    }
}

extern "C" void kernel_launch(void* const* d_in, const int* in_sizes, int n_in,
                              void* d_out, int out_size, void* d_ws, size_t ws_size,
                              hipStream_t stream) {
    KP p;
    p.x_temp  = (const float*)d_in[0];
    p.x_stat  = (const float*)d_in[1];
    p.t       = (const float*)d_in[2];
    p.lengths = (const int*)d_in[4];
    p.aw0 = (const float*)d_in[5];
    p.ab0 = (const float*)d_in[6];
    p.ag  = (const float*)d_in[7];
    p.abeta = (const float*)d_in[8];
    p.aw1 = (const float*)d_in[9];
    p.ab1 = (const float*)d_in[10];
    p.tw  = (const float*)d_in[11];
    p.tb  = (const float*)d_in[12];
    p.tg  = (const float*)d_in[13];
    p.tbeta = (const float*)d_in[14];
    p.sw  = (const float*)d_in[15];
    p.sb  = (const float*)d_in[16];
    p.sg  = (const float*)d_in[17];
    p.sbeta = (const float*)d_in[18];
    p.lw_t = (const float*)d_in[19];
    p.lb_t = (const float*)d_in[20];
    p.lg_t = (const float*)d_in[21];
    p.lbeta_t = (const float*)d_in[22];
    p.lw_s = (const float*)d_in[23];
    p.lb_s = (const float*)d_in[24];
    p.lg_s = (const float*)d_in[25];
    p.lbeta_s = (const float*)d_in[26];
    p.cw = (const float*)d_in[27];
    p.cb = (const float*)d_in[28];

    float* ws = (float*)d_ws;
    p.XL  = ws;                                             // B*T*64 floats
    p.XL2 = ws + (size_t)B * T * TEMP_H;                    // B*T*64 floats
    p.cand = (unsigned long long*)(ws + 2 * (size_t)B * T * TEMP_H);
    p.f1  = (unsigned*)(p.cand + B * NT2 * 8);
    p.f2  = p.f1 + B * NT2 * 16;
    p.arr = p.f2 + B * NT2 * 16;
    p.out = (float*)d_out;
    p.outmax = p.out + (size_t)B * T * N_CLS;

    size_t flagbytes = (size_t)B * NT2 * 8 * 8 + 2 * (size_t)B * NT2 * 16 * 4 + (size_t)B * 16 * 4;
    hipMemsetAsync(p.cand, 0, flagbytes, stream);

    void* args[] = { (void*)&p };
    hipError_t err = hipLaunchCooperativeKernel((const void*)k_run<3>, dim3(NBLK),
                                                dim3(512), args, 0, stream);
    if (err != hipSuccess) {
        (void)hipGetLastError();   // deterministic fallback: 3 ordinary launches
        k_run<0><<<NBLK, 512, 0, stream>>>(p);
        k_run<1><<<NBLK, 512, 0, stream>>>(p);
        k_run<2><<<NBLK, 512, 0, stream>>>(p);
    }
}

// Round 12
// 101.087 us; speedup vs baseline: 1.0342x; 1.0342x over previous
//
#include <hip/hip_runtime.h>

#define B 8
#define T 512
#define TEMP_IN 32
#define STAT_IN 16
#define TEMP_H 64
#define STAT_H 32
#define ATTN_H 32
#define N_CLS 2
#define BN_INV 0.99999500003749969f
#define R 4                  // query rows per tile
#define NTILE (T / R)        // 128 tiles per batch; grid = B*NTILE = 1024 blocks

struct KP {
    const float *x_temp, *x_stat, *t;
    const int* lengths;
    const float *aw0, *ab0, *ag, *abeta, *aw1, *ab1;
    const float *tw, *tb, *tg, *tbeta;
    const float *sw, *sb, *sg, *sbeta;
    const float *lw_t, *lb_t, *lg_t, *lbeta_t;
    const float *lw_s, *lb_s, *lg_s, *lbeta_s;
    const float *cw, *cb;
    float *XL, *XL2;
    unsigned long long* cand;   // [B*NTILE*8]  (64B-padded candidate per tile)
    unsigned *f1, *f2;          // [B*NTILE*16] (64B-padded flag per tile, per sync)
    unsigned *arr;              // [B*16]       (64B-padded last-arriver counter)
    float *out, *outmax;
};

__device__ __forceinline__ float lrelu(float x) {
    return fmaxf(x, 0.01f * x);
}
__device__ __forceinline__ float wave_max(float x) {
    #pragma unroll
    for (int o = 32; o > 0; o >>= 1) x = fmaxf(x, __shfl_xor(x, o));
    return x;
}
__device__ __forceinline__ float wave_sum(float x) {
    #pragma unroll
    for (int o = 32; o > 0; o >>= 1) x += __shfl_xor(x, o);
    return x;
}
__device__ __forceinline__ unsigned ordf(float f) {
    unsigned u = __float_as_uint(f);
    return (u & 0x80000000u) ? ~u : (u | 0x80000000u);
}
__device__ __forceinline__ void stg_llc(float* p, float v) {
    __hip_atomic_store(p, v, __ATOMIC_RELAXED, __HIP_MEMORY_SCOPE_AGENT);
}
__device__ __forceinline__ float ldg_llc(const float* p) {
    return __hip_atomic_load(p, __ATOMIC_RELAXED, __HIP_MEMORY_SCOPE_AGENT);
}
__device__ __forceinline__ void drain_vm() {
    asm volatile("s_waitcnt vmcnt(0)" ::: "memory");
}
__device__ __forceinline__ void fence_acq_wg() {
    __builtin_amdgcn_fence(__ATOMIC_ACQUIRE, "workgroup");
}

struct Shm {
    float att[R][T];                  // 8 KB
    float part[4][R][TEMP_H];         // 4 KB
    float xi[R][TEMP_H];              // 1 KB
    float x1[R][TEMP_H];              // 1 KB
    float t_s[T];                     // 2 KB
    float s_w[3 * ATTN_H + 1];
    float xs[3][STAT_H];
    float xr[4][TEMP_IN];
    float h0s[4][TEMP_H + STAT_H];
    float o_rc[R][2];
    int lastf;
};

// ---- batch sync (width 128): waitcnt + own-flag store; relaxed spin + wg acquire ----
__device__ __forceinline__ void publish(unsigned* f) {
    drain_vm();
    __syncthreads();
    if (threadIdx.x == 0)
        __hip_atomic_store(f, 1u, __ATOMIC_RELAXED, __HIP_MEMORY_SCOPE_AGENT);
}
__device__ __forceinline__ void wait_batch(const unsigned* fbase, int tid) {
    if (tid < NTILE) {   // 128 lanes poll in parallel
        const unsigned* p = fbase + tid * 16;
        while (__hip_atomic_load(p, __ATOMIC_RELAXED, __HIP_MEMORY_SCOPE_AGENT) == 0u)
            __builtin_amdgcn_s_sleep(4);
    }
    __syncthreads();
    fence_acq_wg();
}

// ---- front MLP: encoder + layer0, one row per wave -> XL (LLC) ----
__device__ __forceinline__ void front(const KP& P, Shm& S, int b, int i0, int len,
                                      int lane, int wave) {
    int i = i0 + wave;
    int row = b * T + i;
    if (lane < TEMP_IN) S.xr[wave][lane] = P.x_temp[row * TEMP_IN + lane];
    __syncthreads();
    float acc = P.tb[lane];
    #pragma unroll
    for (int k = 0; k < TEMP_IN; ++k) acc += S.xr[wave][k] * P.tw[k * TEMP_H + lane];
    acc = acc * (P.tg[lane] * BN_INV) + P.tbeta[lane];
    S.h0s[wave][lane] = lrelu(acc);
    if (lane < STAT_H) S.h0s[wave][TEMP_H + lane] = S.xs[0][lane];
    __syncthreads();
    float a2 = P.lb_t[lane];
    #pragma unroll
    for (int k = 0; k < TEMP_H + STAT_H; ++k) a2 += S.h0s[wave][k] * P.lw_t[k * TEMP_H + lane];
    a2 = a2 * (P.lg_t[lane] * BN_INV) + P.lbeta_t[lane];
    a2 = lrelu(a2);
    stg_llc(&P.XL[(size_t)row * TEMP_H + lane], (i < len) ? a2 : 0.f);
    __syncthreads();
}

// ---- temp-attn softmax: one row per wave -> registers ----
__device__ __forceinline__ void temp_compute(Shm& S, float tmpv[8], float inv_dt,
                                             int i0, int len, int lane, int wave) {
    float ab1v = S.s_w[3 * ATTN_H];
    float ti = S.t_s[i0 + wave];
    float a[8], dtq[8];
    #pragma unroll
    for (int q = 0; q < 8; ++q) {
        dtq[q] = (S.t_s[lane + q * 64] - ti) * inv_dt;
        a[q] = ab1v;
    }
    #pragma unroll 4
    for (int k = 0; k < ATTN_H; ++k) {
        float Wk = S.s_w[k];
        float Ck = S.s_w[ATTN_H + k];
        float w1k = S.s_w[2 * ATTN_H + k];
        #pragma unroll
        for (int q = 0; q < 8; ++q) {
            float h = dtq[q] * Wk + Ck;
            h = fmaxf(h, 0.01f * h);
            a[q] += h * w1k;
        }
    }
    float m2 = -1e30f;
    #pragma unroll
    for (int q = 0; q < 8; ++q) {
        int j = lane + q * 64;
        a[q] = (j < len) ? a[q] : -9e8f;
        m2 = fmaxf(m2, a[q]);
    }
    m2 = wave_max(m2);
    float s2 = 0.f;
    #pragma unroll
    for (int q = 0; q < 8; ++q) { a[q] = __expf(a[q] - m2); s2 += a[q]; }
    s2 = wave_sum(s2);
    float inv2 = 1.0f / s2;
    #pragma unroll
    for (int q = 0; q < 8; ++q) tmpv[q] = a[q] * inv2;
}

// ---- attention core; EPI 0: layer1-MLP -> XL2 (+ stage xi); EPI 1: classifier + argmax ----
template <int EPI, bool LOAD_XI>
__device__ __forceinline__ void attn_core(const KP& P, Shm& S, const float* src,
                                          const float tmpv[8],
                                          int b, int i0, int len, int tid, int lane, int wave,
                                          int blk_id) {
    if (LOAD_XI) {
        if (tid < R * TEMP_H)
            S.xi[tid >> 6][tid & 63] = src[((size_t)(b * T + i0 + (tid >> 6))) * TEMP_H + (tid & 63)];
    }
    __syncthreads();
    // qk
    for (int j = tid; j < T; j += 256) {
        const float4* xj4 = reinterpret_cast<const float4*>(&src[((size_t)(b * T + j)) * TEMP_H]);
        float acc[R];
        #pragma unroll
        for (int r = 0; r < R; ++r) acc[r] = 0.f;
        #pragma unroll
        for (int c4 = 0; c4 < TEMP_H / 4; ++c4) {
            float4 xv = xj4[c4];
            #pragma unroll
            for (int r = 0; r < R; ++r) {
                float4 xi4 = *reinterpret_cast<const float4*>(&S.xi[r][c4 * 4]);
                acc[r] += xi4.x * xv.x + xi4.y * xv.y + xi4.z * xv.z + xi4.w * xv.w;
            }
        }
        #pragma unroll
        for (int r = 0; r < R; ++r) S.att[r][j] = acc[r] * 0.125f;
    }
    __syncthreads();
    // softmax(qk) + register temp_attn, mask_j — one row per wave
    {
        int r = wave;
        float v[8];
        float m = -1e30f;
        #pragma unroll
        for (int q = 0; q < 8; ++q) { v[q] = S.att[r][lane + q * 64]; m = fmaxf(m, v[q]); }
        m = wave_max(m);
        float s = 0.f;
        #pragma unroll
        for (int q = 0; q < 8; ++q) { v[q] = __expf(v[q] - m); s += v[q]; }
        s = wave_sum(s);
        float invs = 1.0f / s;
        #pragma unroll
        for (int q = 0; q < 8; ++q) {
            int j = lane + q * 64;
            S.att[r][j] = (j < len) ? (v[q] * invs + tmpv[q]) : 0.f;
        }
    }
    __syncthreads();
    // PV: 4-j register blocking
    float acc2[R];
    #pragma unroll
    for (int r = 0; r < R; ++r) acc2[r] = 0.f;
    {
        const float* srow = src + (size_t)b * T * TEMP_H + lane;
        int j0 = wave * 128;
        for (int g = 0; g < 32; ++g) {
            int j = j0 + g * 4;
            float xv0 = srow[(size_t)(j + 0) * TEMP_H];
            float xv1 = srow[(size_t)(j + 1) * TEMP_H];
            float xv2 = srow[(size_t)(j + 2) * TEMP_H];
            float xv3 = srow[(size_t)(j + 3) * TEMP_H];
            #pragma unroll
            for (int r = 0; r < R; ++r) {
                float4 a4 = *reinterpret_cast<const float4*>(&S.att[r][j]);
                acc2[r] += a4.x * xv0 + a4.y * xv1 + a4.z * xv2 + a4.w * xv3;
            }
        }
    }
    #pragma unroll
    for (int r = 0; r < R; ++r) S.part[wave][r][lane] = acc2[r];
    __syncthreads();
    {   // x1: one (r,cc) per thread
        int r = wave, cc = lane;
        float sum = S.part[0][r][cc] + S.part[1][r][cc] + S.part[2][r][cc] + S.part[3][r][cc];
        S.x1[r][cc] = ((i0 + r) < len) ? sum : 0.f;
    }
    __syncthreads();

    if (EPI == 0) {
        const float* lw1    = P.lw_t + (TEMP_H + STAT_H) * TEMP_H;
        const float* lb1    = P.lb_t + TEMP_H;
        const float* lg1    = P.lg_t + TEMP_H;
        const float* lbeta1 = P.lbeta_t + TEMP_H;
        int r = wave;
        int i = i0 + r;
        float acc = lb1[lane];
        #pragma unroll
        for (int k = 0; k < TEMP_H; ++k) acc += S.x1[r][k] * lw1[k * TEMP_H + lane];
        #pragma unroll
        for (int k = 0; k < STAT_H; ++k) acc += S.xs[1][k] * lw1[(TEMP_H + k) * TEMP_H + lane];
        acc = acc * (lg1[lane] * BN_INV) + lbeta1[lane];
        acc = lrelu(acc);
        float vout = (i < len) ? acc : 0.f;
        stg_llc(&P.XL2[((size_t)(b * T + i)) * TEMP_H + lane], vout);
        __syncthreads();
        S.xi[r][lane] = vout;   // stage 2's query rows — skip the reload
    } else {
        if (tid < R * N_CLS) {
            int r = tid >> 1, cls = tid & 1;
            int i = i0 + r;
            float o = P.cb[cls];
            #pragma unroll
            for (int k = 0; k < TEMP_H; ++k) o += S.x1[r][k] * P.cw[k * N_CLS + cls];
            #pragma unroll
            for (int k = 0; k < STAT_H; ++k) o += S.xs[2][k] * P.cw[(TEMP_H + k) * N_CLS + cls];
            if (i >= len) o = 0.f;
            stg_llc(&P.out[((size_t)(b * T + i)) * N_CLS + cls], o);
            S.o_rc[r][cls] = o;
        }
        __syncthreads();
        if (tid == 0) {
            float best = -3e30f; int bi = i0;
            for (int r = 0; r < R; ++r) {
                int i = i0 + r;
                float diff = (i < len) ? (S.o_rc[r][1] - S.o_rc[r][0]) : -1e30f;
                if (diff > best) { best = diff; bi = i; }
            }
            unsigned long long pack =
                ((unsigned long long)ordf(best) << 32) | (unsigned)(~(unsigned)bi);
            __hip_atomic_store(&P.cand[blk_id * 8], pack,
                               __ATOMIC_RELAXED, __HIP_MEMORY_SCOPE_AGENT);
            drain_vm();
            unsigned old = __hip_atomic_fetch_add(&P.arr[b * 16], 1u,
                                                  __ATOMIC_RELAXED, __HIP_MEMORY_SCOPE_AGENT);
            S.lastf = (old == (NTILE - 1)) ? 1 : 0;
        }
        __syncthreads();
        if (S.lastf) {
            fence_acq_wg();
            if (tid < 64) {
                unsigned long long c0 = __hip_atomic_load(&P.cand[(b * NTILE + tid) * 8],
                                                          __ATOMIC_RELAXED, __HIP_MEMORY_SCOPE_AGENT);
                unsigned long long c1 = __hip_atomic_load(&P.cand[(b * NTILE + 64 + tid) * 8],
                                                          __ATOMIC_RELAXED, __HIP_MEMORY_SCOPE_AGENT);
                unsigned long long c = (c1 > c0) ? c1 : c0;
                #pragma unroll
                for (int o = 32; o > 0; o >>= 1) {
                    unsigned long long oc = __shfl_xor(c, o);
                    c = (oc > c) ? oc : c;
                }
                if (tid == 0) {
                    int idx = (int)(~(unsigned)(c & 0xffffffffu));
                    float o0 = ldg_llc(&P.out[((size_t)(b * T + idx)) * N_CLS + 0]);
                    float o1 = ldg_llc(&P.out[((size_t)(b * T + idx)) * N_CLS + 1]);
                    stg_llc(&P.outmax[b * 2 + 0], o0);
                    stg_llc(&P.outmax[b * 2 + 1], o1);
                }
            }
        }
    }
}

// PHASE: 0 = front only, 1 = stage A only, 2 = stage B only, 3 = fully fused
template <int PHASE>
__global__ void __launch_bounds__(256, 4) k_run(KP P) {
    __shared__ Shm S;
    int tid = threadIdx.x, lane = tid & 63, wave = tid >> 6;
    int blk = blockIdx.x;
    // XCD-affinity swizzle (locality heuristic only; correctness is placement-free).
    int b = blk & 7, tile = blk >> 3, i0 = tile * R;
    int blk_id = b * NTILE + tile;
    int len = P.lengths[b];
    float tmpv[8];

    // xs0 (stat encoder)
    if (tid < STAT_H) {
        float acc = P.sb[tid];
        #pragma unroll
        for (int k = 0; k < STAT_IN; ++k) acc += P.x_stat[b * STAT_IN + k] * P.sw[k * STAT_H + tid];
        acc = acc * (P.sg[tid] * BN_INV) + P.sbeta[tid];
        S.xs[0][tid] = lrelu(acc);
    }
    __syncthreads();

    if (PHASE == 0 || PHASE == 3) front(P, S, b, i0, len, lane, wave);
    if (PHASE == 3) publish(&P.f1[blk_id * 16]);

    if (PHASE != 0) {
        if (tid < ATTN_H) {
            float g = P.ag[tid] * BN_INV;
            S.s_w[tid]              = P.aw0[tid] * g;
            S.s_w[ATTN_H + tid]     = P.ab0[tid] * g + P.abeta[tid];
            S.s_w[2 * ATTN_H + tid] = P.aw1[tid];
        }
        if (tid == 0) S.s_w[3 * ATTN_H] = P.ab1[0];
        S.t_s[tid] = P.t[b * T + tid];
        S.t_s[tid + 256] = P.t[b * T + tid + 256];
        float d = P.t[(lane & 7) * T + (T - 1)] - P.t[(lane & 7) * T];
        d = wave_max(d);
        float inv_dt = 1.0f / (d + 1e-8f);
        __syncthreads();
        if (tid < STAT_H) {   // xs1
            float a2 = P.lb_s[tid];
            #pragma unroll
            for (int k = 0; k < STAT_H; ++k) a2 += S.xs[0][k] * P.lw_s[k * STAT_H + tid];
            a2 = a2 * (P.lg_s[tid] * BN_INV) + P.lbeta_s[tid];
            S.xs[1][tid] = lrelu(a2);
        }
        __syncthreads();
        if (tid < STAT_H) {   // xs2
            float a2 = P.lb_s[STAT_H + tid];
            #pragma unroll
            for (int k = 0; k < STAT_H; ++k) a2 += S.xs[1][k] * P.lw_s[(STAT_H + k) * STAT_H + tid];
            a2 = a2 * (P.lg_s[STAT_H + tid] * BN_INV) + P.lbeta_s[STAT_H + tid];
            S.xs[2][tid] = lrelu(a2);
        }
        __syncthreads();
        temp_compute(S, tmpv, inv_dt, i0, len, lane, wave);   // overlaps f1 wait
        __syncthreads();
    }

    if (PHASE == 3) wait_batch(P.f1 + b * NTILE * 16, tid);
    if (PHASE == 1 || PHASE == 3)
        attn_core<0, true>(P, S, P.XL, tmpv, b, i0, len, tid, lane, wave, blk_id);
    if (PHASE == 3) {
        publish(&P.f2[blk_id * 16]);
        wait_batch(P.f2 + b * NTILE * 16, tid);
        attn_core<1, false>(P, S, P.XL2, tmpv, b, i0, len, tid, lane, wave, blk_id);
    } else if (PHASE == 2) {
        attn_core<1, true>(P, S, P.XL2, tmpv, b, i0, len, tid, lane, wave, blk_id);
    }
}

extern "C" void kernel_launch(void* const* d_in, const int* in_sizes, int n_in,
                              void* d_out, int out_size, void* d_ws, size_t ws_size,
                              hipStream_t stream) {
    KP p;
    p.x_temp  = (const float*)d_in[0];
    p.x_stat  = (const float*)d_in[1];
    p.t       = (const float*)d_in[2];
    p.lengths = (const int*)d_in[4];
    p.aw0 = (const float*)d_in[5];
    p.ab0 = (const float*)d_in[6];
    p.ag  = (const float*)d_in[7];
    p.abeta = (const float*)d_in[8];
    p.aw1 = (const float*)d_in[9];
    p.ab1 = (const float*)d_in[10];
    p.tw  = (const float*)d_in[11];
    p.tb  = (const float*)d_in[12];
    p.tg  = (const float*)d_in[13];
    p.tbeta = (const float*)d_in[14];
    p.sw  = (const float*)d_in[15];
    p.sb  = (const float*)d_in[16];
    p.sg  = (const float*)d_in[17];
    p.sbeta = (const float*)d_in[18];
    p.lw_t = (const float*)d_in[19];
    p.lb_t = (const float*)d_in[20];
    p.lg_t = (const float*)d_in[21];
    p.lbeta_t = (const float*)d_in[22];
    p.lw_s = (const float*)d_in[23];
    p.lb_s = (const float*)d_in[24];
    p.lg_s = (const float*)d_in[25];
    p.lbeta_s = (const float*)d_in[26];
    p.cw = (const float*)d_in[27];
    p.cb = (const float*)d_in[28];

    float* ws = (float*)d_ws;
    p.XL  = ws;                                             // B*T*64 floats
    p.XL2 = ws + (size_t)B * T * TEMP_H;                    // B*T*64 floats
    p.cand = (unsigned long long*)(ws + 2 * (size_t)B * T * TEMP_H);
    p.f1  = (unsigned*)(p.cand + B * NTILE * 8);
    p.f2  = p.f1 + B * NTILE * 16;
    p.arr = p.f2 + B * NTILE * 16;
    p.out = (float*)d_out;
    p.outmax = p.out + (size_t)B * T * N_CLS;

    size_t flagbytes = (size_t)B * NTILE * 8 * 8
                     + 2 * (size_t)B * NTILE * 16 * 4 + (size_t)B * 16 * 4;
    hipMemsetAsync(p.cand, 0, flagbytes, stream);

    void* args[] = { (void*)&p };
    hipError_t err = hipLaunchCooperativeKernel((const void*)k_run<3>, dim3(B * NTILE),
                                                dim3(256), args, 0, stream);
    if (err != hipSuccess) {
        (void)hipGetLastError();   // deterministic fallback: 3 ordinary launches
        k_run<0><<<B * NTILE, 256, 0, stream>>>(p);
        k_run<1><<<B * NTILE, 256, 0, stream>>>(p);
        k_run<2><<<B * NTILE, 256, 0, stream>>>(p);
    }
}